// Round 10
// baseline (367.486 us; speedup 1.0000x reference)
//
#include <hip/hip_runtime.h>
#include <cstdint>
#include <cstddef>

#define E_DIM   1024
#define B_DIM   1024
#define HPITCH  1040          // h-buffer row pitch (elems): breaks 2KB power-of-2
                              // stride so 16-row strided A-loads spread L1 sets
#define T_STEPS 10
#define OUT_DIM 34
#define OUT_PAD 48
#define HSTR    24            // h-transpose LDS row stride (16 cols + pad)
#define WSLICE  65536         // full per-bn W slice, elems (128 KB)
#define WHALF   32768         // half slice, elems (64 KB)
#define HT_ROWS 256
#define DYN_LDS (WSLICE * 2 + HT_ROWS * HSTR * 2)     // 131072 + 12288 = 143360 B
#define HSLOT  ((size_t)B_DIM * HPITCH)               // elems per h slot

typedef __attribute__((ext_vector_type(4))) float  f32x4;
typedef __attribute__((ext_vector_type(8))) __bf16 bf16x8;

__device__ __forceinline__ unsigned short f2bf(float f) {
    unsigned int u = __float_as_uint(f);
    u = (u + 0x7FFFu + ((u >> 16) & 1u)) >> 16;   // round-to-nearest-even
    return (unsigned short)u;
}
__device__ __forceinline__ float sigmoid_(float x) { return 1.0f / (1.0f + __expf(-x)); }
__device__ __forceinline__ float tanh_(float x)    { return 2.0f / (1.0f + __expf(-2.0f * x)) - 1.0f; }

// Merged prep: blocks 0..511 emit weights in MFMA-B-fragment order
//   WF[bn(64)][qtr(4)][ks8(8)][nt(4)][lane(64)][8 elems]
// blocks 512..2623: h0->bf16 (pitch HPITCH), W_out->bf16 padded, bias permuted,
// c permuted into the MFMA-accumulator flat layout (same formulas as verified).
__global__ void prep_all(const float* __restrict__ W_ih, const float* __restrict__ W_hh,
                         const float* __restrict__ h0, const float* __restrict__ c0,
                         const float* __restrict__ W_out,
                         const float* __restrict__ b_ih, const float* __restrict__ b_hh,
                         unsigned short* __restrict__ WsumF, unsigned short* __restrict__ WhhF,
                         unsigned short* __restrict__ hbuf, unsigned short* __restrict__ Woutp,
                         float* __restrict__ bperm, float* __restrict__ C) {
    const int blk = blockIdx.x;
    const int t = threadIdx.x;
    if (blk < 512) {
        const int bn = blk >> 3, qtr = (blk >> 1) & 3, half = blk & 1;
        const int nt = t >> 6, lane = t & 63;
        const int j = lane & 15, q = lane >> 4;
        const int srow = nt * E_DIM + bn * 16 + j;
        const float* wi = W_ih + (size_t)srow * E_DIM;
        const float* wh = W_hh + (size_t)srow * E_DIM;
        const size_t dstb = (size_t)bn * 65536 + (size_t)qtr * 16384 + nt * 512 + lane * 8;
#pragma unroll
        for (int ks8i = 0; ks8i < 4; ++ks8i) {
            const int ks8 = half * 4 + ks8i;
            const int k = qtr * 256 + ks8 * 32 + q * 8;
            float4 i0 = *(const float4*)(wi + k);
            float4 i1 = *(const float4*)(wi + k + 4);
            float4 h0v = *(const float4*)(wh + k);
            float4 h1v = *(const float4*)(wh + k + 4);
            unsigned short* ds = WsumF + dstb + ks8 * 2048;
            unsigned short* dh = WhhF  + dstb + ks8 * 2048;
            ds[0] = f2bf(i0.x + h0v.x); ds[1] = f2bf(i0.y + h0v.y);
            ds[2] = f2bf(i0.z + h0v.z); ds[3] = f2bf(i0.w + h0v.w);
            ds[4] = f2bf(i1.x + h1v.x); ds[5] = f2bf(i1.y + h1v.y);
            ds[6] = f2bf(i1.z + h1v.z); ds[7] = f2bf(i1.w + h1v.w);
            dh[0] = f2bf(h0v.x); dh[1] = f2bf(h0v.y); dh[2] = f2bf(h0v.z); dh[3] = f2bf(h0v.w);
            dh[4] = f2bf(h1v.x); dh[5] = f2bf(h1v.y); dh[6] = f2bf(h1v.z); dh[7] = f2bf(h1v.w);
        }
        return;
    }
    const int b = blk - 512;                        // 0..2111 (verified prep_state map)
    if (b < 1024) {
        const size_t src = ((size_t)b * 256 + t) * 4;
        float4 hv = *(const float4*)(h0 + src);
        const size_t i = (size_t)b * HPITCH + t * 4;
        hbuf[i + 0] = f2bf(hv.x);
        hbuf[i + 1] = f2bf(hv.y);
        hbuf[i + 2] = f2bf(hv.z);
        hbuf[i + 3] = f2bf(hv.w);
    } else if (b < 1072) {
        const int o = b - 1024;                     // 0..47
        const int k = t * 4;
        float4 w = make_float4(0.f, 0.f, 0.f, 0.f);
        if (o < OUT_DIM) w = *(const float4*)(W_out + (size_t)o * E_DIM + k);
        const size_t dst = (size_t)o * E_DIM + k;
        Woutp[dst + 0] = f2bf(w.x);
        Woutp[dst + 1] = f2bf(w.y);
        Woutp[dst + 2] = f2bf(w.z);
        Woutp[dst + 3] = f2bf(w.w);
    } else if (b < 1088) {
        const int n = (b - 1072) * 256 + t;         // 0..4095
        const int g = (n >> 4) & 3;
        const int e = ((n >> 6) << 4) | (n & 15);
        const int srow = g * E_DIM + e;
        bperm[n] = b_ih[srow] + b_hh[srow];
    } else {
        const int m = b - 1088;                     // 0..1023
        const int e0 = t * 4;
        float4 v = *(const float4*)(c0 + (size_t)m * E_DIM + e0);
        const int bm = m >> 7, wave = (m >> 5) & 3, mt = (m >> 4) & 1, q = (m >> 2) & 3, r = m & 3;
        const float vv[4] = {v.x, v.y, v.z, v.w};
#pragma unroll
        for (int ii = 0; ii < 4; ++ii) {
            const int e = e0 + ii;
            const int bn = e >> 4, jj = e & 15;
            const int lane = q * 16 + jj;
            C[(((size_t)(bn * 8 + bm) * 4 + wave) * 64 + lane) * 8 + mt * 4 + r] = vv[ii];
        }
    }
}

// One fused LSTM step. Grid (64, 4) = 256 blocks (1/CU), 512 threads = 8 waves.
// Block (bn,g): 64 permuted N-rows x 256 batch rows. Single 128 KB LDS W buffer.
// HALF-SPLIT staging (issue-early / write-late): stage half 0 (64 KB) before the
// first barrier (halves the serial vmcnt(0) drain vs full-slice, R9); half 1's
// global loads are ISSUED at the start of quarter-0 compute and land under
// ~2 quarters of MFMA work; ds_write + one barrier commits them before qtr 2.
// A-loads at pitch HPITCH (L1-set-safe, R8). C layout compat with prep via
// m = g*256 + w*32 + mt*16 + q*4 + r <=> old (bm = g*2 + (w>>2), wave = w&3).
__global__ __launch_bounds__(512, 2) void lstm_step(
    const unsigned short* __restrict__ WF,   // [64][4][8][4][64][8] bf16 fragment-order
    const float* __restrict__ bp,            // [4096] permuted bias
    const unsigned short* __restrict__ Hin,  // [1024][HPITCH] bf16
    float* __restrict__ C,                   // [B*E] f32 cell state in MFMA layout
    unsigned short* __restrict__ Hout)       // [1024][HPITCH] bf16
{
    extern __shared__ __align__(16) unsigned short smem[];
    unsigned short* Wlds = smem;                     // 128 KB: full slice
    unsigned short* Ht   = smem + WSLICE;            // 256 x HSTR (12 KB)

    const int tid  = threadIdx.x;
    const int w    = tid >> 6;                       // 0..7
    const int lane = tid & 63;
    const int bn = blockIdx.x;
    const int g  = blockIdx.y;                       // 0..3
    const int j  = lane & 15;
    const int q  = lane >> 4;

    f32x4 acc[2][4];
#pragma unroll
    for (int a = 0; a < 2; ++a)
#pragma unroll
        for (int b = 0; b < 4; ++b) acc[a][b] = (f32x4){0.f, 0.f, 0.f, 0.f};

    // hoisted far-from-use loads: biases + old cell state
    const int nb = bn * 64 + j;
    const float bi = bp[nb +  0];
    const float bf = bp[nb + 16];
    const float bg = bp[nb + 32];
    const float bo = bp[nb + 48];
    const int obm = g * 2 + (w >> 2), owv = w & 3;   // old-coords for C layout
    const size_t cbase = (((size_t)(bn * 8 + obm) * 4 + owv) * 64 + lane) * 8;
    float4 cold0 = *(const float4*)(C + cbase);
    float4 cold1 = *(const float4*)(C + cbase + 4);

    // A row base (per mt): m = g*256 + w*32 + mt*16 + j
    const unsigned short* arow0 = Hin + (size_t)(g * 256 + w * 32 + j) * HPITCH + q * 8;
    const unsigned short* arow1 = arow0 + (size_t)16 * HPITCH;
    const unsigned short* wsrc  = WF + (size_t)bn * WSLICE;   // this block's 128 KB slice

    // stage HALF 0 (qtr 0,1): 512 threads x 8 x 16 B
    uint4 wreg[8];
#pragma unroll
    for (int i = 0; i < 8; ++i)
        wreg[i] = *(const uint4*)(wsrc + (i * 512 + tid) * 8);
#pragma unroll
    for (int i = 0; i < 8; ++i)
        *(uint4*)(Wlds + (i * 512 + tid) * 8) = wreg[i];

    // A pipeline, depth 8 (covers L2/L3 latency; issued under staging waits)
    uint4 ra[8][2];
#pragma unroll
    for (int p = 0; p < 8; ++p) {
        ra[p][0] = *(const uint4*)(arow0 + p * 32);
        ra[p][1] = *(const uint4*)(arow1 + p * 32);
    }
    __syncthreads();    // half 0 in LDS (64 KB drain, half of R9's)

    for (int half = 0; half < 2; ++half) {
        if (half == 0) {
            // issue half-1 loads now; they land under quarters 0-1 of compute
#pragma unroll
            for (int i = 0; i < 8; ++i)
                wreg[i] = *(const uint4*)(wsrc + WHALF + (i * 512 + tid) * 8);
        }
#pragma unroll
        for (int qq = 0; qq < 2; ++qq) {
            const int qtr = half * 2 + qq;
            const unsigned short* wb = Wlds + qtr * 16384 + lane * 8;
#pragma unroll
            for (int ks8 = 0; ks8 < 8; ++ks8) {
                const int ks = qtr * 8 + ks8;
                bf16x8 av0 = __builtin_bit_cast(bf16x8, ra[ks8][0]);
                bf16x8 av1 = __builtin_bit_cast(bf16x8, ra[ks8][1]);
                bf16x8 bv[4];
#pragma unroll
                for (int nt = 0; nt < 4; ++nt)
                    bv[nt] = *(const bf16x8*)(wb + (ks8 * 4 + nt) * 512);   // imm offset
#pragma unroll
                for (int nt = 0; nt < 4; ++nt) {
                    acc[0][nt] = __builtin_amdgcn_mfma_f32_16x16x32_bf16(av0, bv[nt], acc[0][nt], 0, 0, 0);
                    acc[1][nt] = __builtin_amdgcn_mfma_f32_16x16x32_bf16(av1, bv[nt], acc[1][nt], 0, 0, 0);
                }
                if (ks < 24) {                  // keep the 8-deep A pipeline full
                    ra[ks8][0] = *(const uint4*)(arow0 + (ks + 8) * 32);
                    ra[ks8][1] = *(const uint4*)(arow1 + (ks + 8) * 32);
                }
            }
        }
        if (half == 0) {
            // commit half 1 (loads have had ~2 quarters to land -> cheap waits)
#pragma unroll
            for (int i = 0; i < 8; ++i)
                *(uint4*)(Wlds + WHALF + (i * 512 + tid) * 8) = wreg[i];
            __syncthreads();
        }
    }

    // ---- Epilogue: nt is the gate index (i,f,g,o); lane-local LSTM update ----
    float4 cnew[2];
    const float coldv[2][4] = {{cold0.x, cold0.y, cold0.z, cold0.w},
                               {cold1.x, cold1.y, cold1.z, cold1.w}};
#pragma unroll
    for (int mt = 0; mt < 2; ++mt) {
#pragma unroll
        for (int r = 0; r < 4; ++r) {
            const float iv = sigmoid_(acc[mt][0][r] + bi);
            const float fv = sigmoid_(acc[mt][1][r] + bf);
            const float gv = tanh_(acc[mt][2][r] + bg);
            const float ov = sigmoid_(acc[mt][3][r] + bo);
            const float cn = fv * coldv[mt][r] + iv * gv;
            cnew[mt][r] = cn;
            const int rowl = w * 32 + mt * 16 + q * 4 + r;   // 0..255
            Ht[rowl * HSTR + j] = f2bf(ov * tanh_(cn));
        }
    }
    *(float4*)(C + cbase)     = cnew[0];
    *(float4*)(C + cbase + 4) = cnew[1];
    __syncthreads();

    // coalesced h store: 2 threads per row, 16B each (512 thr = 256 rows x 2)
    {
        const int row = tid >> 1, part = tid & 1;
        uint4 v = *(const uint4*)(Ht + row * HSTR + part * 8);
        *(uint4*)(Hout + (size_t)(g * 256 + row) * HPITCH + bn * 16 + part * 8) = v;
    }
}

// Output projection: out[b,t,o] = hs[t+1][b][:] . Wo[o][:] + b_out[o]
__global__ __launch_bounds__(256) void proj_kernel(
    const unsigned short* __restrict__ Hs,   // [T][B][HPITCH] bf16 (slot 1 of hs)
    const unsigned short* __restrict__ Wo,   // [48][E] bf16 (rows >=34 zero)
    const float* __restrict__ b_out,         // [34]
    float* __restrict__ Out)                 // [B][T][34]
{
    __shared__ float red[4][32][OUT_PAD];    // 24 KB

    const int tid = threadIdx.x, wave = tid >> 6, lane = tid & 63;
    const int j = lane & 15, q = lane >> 4;
    const int t  = blockIdx.y;
    const int bb = blockIdx.x;
    const unsigned short* Hbase = Hs + (size_t)t * HSLOT + (size_t)bb * 32 * HPITCH;
    const int k0 = wave * 256;

    f32x4 acc[2][3];
#pragma unroll
    for (int a = 0; a < 2; ++a)
#pragma unroll
        for (int b = 0; b < 3; ++b) acc[a][b] = (f32x4){0.f, 0.f, 0.f, 0.f};

#pragma unroll
    for (int kk = 0; kk < 256; kk += 32) {
        const int kc = k0 + kk + q * 8;
        bf16x8 av[2], bv[3];
#pragma unroll
        for (int mt = 0; mt < 2; ++mt)
            av[mt] = *(const bf16x8*)(Hbase + (size_t)(mt * 16 + j) * HPITCH + kc);
#pragma unroll
        for (int nt = 0; nt < 3; ++nt)
            bv[nt] = *(const bf16x8*)(Wo + (size_t)(nt * 16 + j) * E_DIM + kc);
#pragma unroll
        for (int mt = 0; mt < 2; ++mt)
#pragma unroll
            for (int nt = 0; nt < 3; ++nt)
                acc[mt][nt] = __builtin_amdgcn_mfma_f32_16x16x32_bf16(av[mt], bv[nt], acc[mt][nt], 0, 0, 0);
    }

#pragma unroll
    for (int mt = 0; mt < 2; ++mt)
#pragma unroll
        for (int nt = 0; nt < 3; ++nt)
#pragma unroll
            for (int r = 0; r < 4; ++r)
                red[wave][mt * 16 + q * 4 + r][nt * 16 + j] = acc[mt][nt][r];
    __syncthreads();

#pragma unroll
    for (int ii = 0; ii < 6; ++ii) {
        const int idx = tid * 6 + ii;            // 0..1535 = 32 rows x 48 outs
        const int row = idx / OUT_PAD, o = idx % OUT_PAD;
        if (o < OUT_DIM) {
            const float s = red[0][row][o] + red[1][row][o] + red[2][row][o] + red[3][row][o];
            Out[((size_t)(bb * 32 + row) * T_STEPS + t) * OUT_DIM + o] = s + b_out[o];
        }
    }
}

extern "C" void kernel_launch(void* const* d_in, const int* in_sizes, int n_in,
                              void* d_out, int out_size, void* d_ws, size_t ws_size,
                              hipStream_t stream) {
    (void)in_sizes; (void)n_in; (void)out_size; (void)ws_size;
    const float* h     = (const float*)d_in[0];
    const float* c     = (const float*)d_in[1];
    const float* W_ih  = (const float*)d_in[2];
    const float* W_hh  = (const float*)d_in[3];
    const float* b_ih  = (const float*)d_in[4];
    const float* b_hh  = (const float*)d_in[5];
    const float* W_out = (const float*)d_in[6];
    const float* b_out = (const float*)d_in[7];
    float* out = (float*)d_out;

    char* ws = (char*)d_ws;
    unsigned short* WsumF = (unsigned short*)(ws + 0);          //  8 MB fragment-order
    unsigned short* WhhF  = (unsigned short*)(ws + 8388608);    //  8 MB fragment-order
    float*          bperm = (float*)(ws + 16777216);            // 16 KB
    unsigned short* Woutp = (unsigned short*)(ws + 16842752);   // 96 KB
    float*          cbuf  = (float*)(ws + 16941056);            //  4 MB (MFMA layout)
    unsigned short* hs    = (unsigned short*)(ws + 21135360);   // ~23.4 MB: slot0=h0, slots1..10

    // host-side attribute set (not a stream op; safe under graph capture)
    hipFuncSetAttribute((const void*)lstm_step,
                        hipFuncAttributeMaxDynamicSharedMemorySize, DYN_LDS);

    prep_all<<<2624, 256, 0, stream>>>(W_ih, W_hh, h, c, W_out, b_ih, b_hh,
                                       WsumF, WhhF, hs, Woutp, bperm, cbuf);

    // step 0: x = 0  ->  W_hh only; steps 1..9: x == h_prev -> fused W_ih + W_hh
    lstm_step<<<dim3(64, 4), 512, DYN_LDS, stream>>>(WhhF, bperm, hs, cbuf, hs + HSLOT);
    for (int t = 1; t < T_STEPS; ++t)
        lstm_step<<<dim3(64, 4), 512, DYN_LDS, stream>>>(WsumF, bperm,
                                                         hs + (size_t)t * HSLOT,
                                                         cbuf,
                                                         hs + (size_t)(t + 1) * HSLOT);

    proj_kernel<<<dim3(32, T_STEPS), 256, 0, stream>>>(hs + HSLOT, Woutp, b_out, out);
}

// Round 11
// 273.096 us; speedup vs baseline: 1.3456x; 1.3456x over previous
//
#include <hip/hip_runtime.h>
#include <cstdint>
#include <cstddef>

#define E_DIM   1024
#define B_DIM   1024
#define HPITCH  1040          // h-buffer row pitch (elems): breaks 2KB power-of-2
                              // stride so 16-row strided A-loads spread L1 sets
#define T_STEPS 10
#define OUT_DIM 34
#define OUT_PAD 48
#define HSTR    24            // h-transpose LDS row stride (16 cols + pad)
#define WSLICE  65536         // full per-bn W slice, elems (128 KB)
#define HT_ROWS 256
#define DYN_LDS (WSLICE * 2 + HT_ROWS * HSTR * 2)     // 131072 + 12288 = 143360 B
#define HSLOT  ((size_t)B_DIM * HPITCH)               // elems per h slot

typedef __attribute__((ext_vector_type(4))) float  f32x4;
typedef __attribute__((ext_vector_type(8))) __bf16 bf16x8;

__device__ __forceinline__ unsigned short f2bf(float f) {
    unsigned int u = __float_as_uint(f);
    u = (u + 0x7FFFu + ((u >> 16) & 1u)) >> 16;   // round-to-nearest-even
    return (unsigned short)u;
}
__device__ __forceinline__ float sigmoid_(float x) { return 1.0f / (1.0f + __expf(-x)); }
__device__ __forceinline__ float tanh_(float x)    { return 2.0f / (1.0f + __expf(-2.0f * x)) - 1.0f; }

// Merged prep: blocks 0..511 emit weights in MFMA-B-fragment order
//   WF[bn(64)][qtr(4)][ks8(8)][nt(4)][lane(64)][8 elems]
// blocks 512..2623: h0->bf16 (pitch HPITCH), W_out->bf16 padded, bias permuted,
// c permuted into the MFMA-accumulator flat layout (same formulas as verified).
// (Single variable vs R9: saves one launch slot; weight/state prep co-scheduled.)
__global__ void prep_all(const float* __restrict__ W_ih, const float* __restrict__ W_hh,
                         const float* __restrict__ h0, const float* __restrict__ c0,
                         const float* __restrict__ W_out,
                         const float* __restrict__ b_ih, const float* __restrict__ b_hh,
                         unsigned short* __restrict__ WsumF, unsigned short* __restrict__ WhhF,
                         unsigned short* __restrict__ hbuf, unsigned short* __restrict__ Woutp,
                         float* __restrict__ bperm, float* __restrict__ C) {
    const int blk = blockIdx.x;
    const int t = threadIdx.x;
    if (blk < 512) {
        const int bn = blk >> 3, qtr = (blk >> 1) & 3, half = blk & 1;
        const int nt = t >> 6, lane = t & 63;
        const int j = lane & 15, q = lane >> 4;
        const int srow = nt * E_DIM + bn * 16 + j;
        const float* wi = W_ih + (size_t)srow * E_DIM;
        const float* wh = W_hh + (size_t)srow * E_DIM;
        const size_t dstb = (size_t)bn * 65536 + (size_t)qtr * 16384 + nt * 512 + lane * 8;
#pragma unroll
        for (int ks8i = 0; ks8i < 4; ++ks8i) {
            const int ks8 = half * 4 + ks8i;
            const int k = qtr * 256 + ks8 * 32 + q * 8;
            float4 i0 = *(const float4*)(wi + k);
            float4 i1 = *(const float4*)(wi + k + 4);
            float4 h0v = *(const float4*)(wh + k);
            float4 h1v = *(const float4*)(wh + k + 4);
            unsigned short* ds = WsumF + dstb + ks8 * 2048;
            unsigned short* dh = WhhF  + dstb + ks8 * 2048;
            ds[0] = f2bf(i0.x + h0v.x); ds[1] = f2bf(i0.y + h0v.y);
            ds[2] = f2bf(i0.z + h0v.z); ds[3] = f2bf(i0.w + h0v.w);
            ds[4] = f2bf(i1.x + h1v.x); ds[5] = f2bf(i1.y + h1v.y);
            ds[6] = f2bf(i1.z + h1v.z); ds[7] = f2bf(i1.w + h1v.w);
            dh[0] = f2bf(h0v.x); dh[1] = f2bf(h0v.y); dh[2] = f2bf(h0v.z); dh[3] = f2bf(h0v.w);
            dh[4] = f2bf(h1v.x); dh[5] = f2bf(h1v.y); dh[6] = f2bf(h1v.z); dh[7] = f2bf(h1v.w);
        }
        return;
    }
    const int b = blk - 512;                        // 0..2111 (verified prep_state map)
    if (b < 1024) {
        const size_t src = ((size_t)b * 256 + t) * 4;
        float4 hv = *(const float4*)(h0 + src);
        const size_t i = (size_t)b * HPITCH + t * 4;
        hbuf[i + 0] = f2bf(hv.x);
        hbuf[i + 1] = f2bf(hv.y);
        hbuf[i + 2] = f2bf(hv.z);
        hbuf[i + 3] = f2bf(hv.w);
    } else if (b < 1072) {
        const int o = b - 1024;                     // 0..47
        const int k = t * 4;
        float4 w = make_float4(0.f, 0.f, 0.f, 0.f);
        if (o < OUT_DIM) w = *(const float4*)(W_out + (size_t)o * E_DIM + k);
        const size_t dst = (size_t)o * E_DIM + k;
        Woutp[dst + 0] = f2bf(w.x);
        Woutp[dst + 1] = f2bf(w.y);
        Woutp[dst + 2] = f2bf(w.z);
        Woutp[dst + 3] = f2bf(w.w);
    } else if (b < 1088) {
        const int n = (b - 1072) * 256 + t;         // 0..4095
        const int g = (n >> 4) & 3;
        const int e = ((n >> 6) << 4) | (n & 15);
        const int srow = g * E_DIM + e;
        bperm[n] = b_ih[srow] + b_hh[srow];
    } else {
        const int m = b - 1088;                     // 0..1023
        const int e0 = t * 4;
        float4 v = *(const float4*)(c0 + (size_t)m * E_DIM + e0);
        const int bm = m >> 7, wave = (m >> 5) & 3, mt = (m >> 4) & 1, q = (m >> 2) & 3, r = m & 3;
        const float vv[4] = {v.x, v.y, v.z, v.w};
#pragma unroll
        for (int ii = 0; ii < 4; ++ii) {
            const int e = e0 + ii;
            const int bn = e >> 4, jj = e & 15;
            const int lane = q * 16 + jj;
            C[(((size_t)(bn * 8 + bm) * 4 + wave) * 64 + lane) * 8 + mt * 4 + r] = vv[ii];
        }
    }
}

// One fused LSTM step — byte-identical to the R9 green kernel (275.6 us).
// Grid (64, 4) = 256 blocks (1/CU), 512 threads = 8 waves.
// Block (bn,g): 64 permuted N-rows (4 gates x 16 e) x 256 batch rows.
// ENTIRE 128 KB W slice staged to LDS once -> ONE barrier, then the whole
// K=1024 MFMA loop is barrier-free. (Half-split staging with early-issued W
// loads regressed +92 us in R10: vmcnt ordering makes every younger A-ring
// wait drain the older in-flight W loads — do NOT reintroduce.)
// A-loads at pitch HPITCH (L1-set-safe, R8). C layout compat with prep via
// m = g*256 + w*32 + mt*16 + q*4 + r <=> old (bm = g*2 + (w>>2), wave = w&3).
__global__ __launch_bounds__(512, 2) void lstm_step(
    const unsigned short* __restrict__ WF,   // [64][4][8][4][64][8] bf16 fragment-order
    const float* __restrict__ bp,            // [4096] permuted bias
    const unsigned short* __restrict__ Hin,  // [1024][HPITCH] bf16
    float* __restrict__ C,                   // [B*E] f32 cell state in MFMA layout
    unsigned short* __restrict__ Hout)       // [1024][HPITCH] bf16
{
    extern __shared__ __align__(16) unsigned short smem[];
    unsigned short* Wlds = smem;                     // 128 KB: full slice
    unsigned short* Ht   = smem + WSLICE;            // 256 x HSTR (12 KB)

    const int tid  = threadIdx.x;
    const int w    = tid >> 6;                       // 0..7
    const int lane = tid & 63;
    const int bn = blockIdx.x;
    const int g  = blockIdx.y;                       // 0..3
    const int j  = lane & 15;
    const int q  = lane >> 4;

    f32x4 acc[2][4];
#pragma unroll
    for (int a = 0; a < 2; ++a)
#pragma unroll
        for (int b = 0; b < 4; ++b) acc[a][b] = (f32x4){0.f, 0.f, 0.f, 0.f};

    // hoisted far-from-use loads: biases + old cell state
    const int nb = bn * 64 + j;
    const float bi = bp[nb +  0];
    const float bf = bp[nb + 16];
    const float bg = bp[nb + 32];
    const float bo = bp[nb + 48];
    const int obm = g * 2 + (w >> 2), owv = w & 3;   // old-coords for C layout
    const size_t cbase = (((size_t)(bn * 8 + obm) * 4 + owv) * 64 + lane) * 8;
    float4 cold0 = *(const float4*)(C + cbase);
    float4 cold1 = *(const float4*)(C + cbase + 4);

    // A row base (per mt): m = g*256 + w*32 + mt*16 + j
    const unsigned short* arow0 = Hin + (size_t)(g * 256 + w * 32 + j) * HPITCH + q * 8;
    const unsigned short* arow1 = arow0 + (size_t)16 * HPITCH;
    const unsigned short* wsrc  = WF + (size_t)bn * WSLICE;   // this block's 128 KB slice

    // stage the FULL W slice: 512 threads x 16 x 16 B, two register rounds of 8
    {
        uint4 wreg[8];
#pragma unroll
        for (int r2 = 0; r2 < 2; ++r2) {
#pragma unroll
            for (int i = 0; i < 8; ++i)
                wreg[i] = *(const uint4*)(wsrc + ((r2 * 8 + i) * 512 + tid) * 8);
#pragma unroll
            for (int i = 0; i < 8; ++i)
                *(uint4*)(Wlds + ((r2 * 8 + i) * 512 + tid) * 8) = wreg[i];
        }
    }

    // A pipeline, depth 8 (covers L2/L3 latency; issued under staging waits)
    uint4 ra[8][2];
#pragma unroll
    for (int p = 0; p < 8; ++p) {
        ra[p][0] = *(const uint4*)(arow0 + p * 32);
        ra[p][1] = *(const uint4*)(arow1 + p * 32);
    }
    __syncthreads();    // the ONLY pre-epilogue barrier: W slice fully in LDS

    for (int qtr = 0; qtr < 4; ++qtr) {
        const unsigned short* wb = Wlds + qtr * 16384 + lane * 8;   // imm stays <32KB
#pragma unroll
        for (int ks8 = 0; ks8 < 8; ++ks8) {
            const int ks = qtr * 8 + ks8;
            bf16x8 av0 = __builtin_bit_cast(bf16x8, ra[ks8][0]);
            bf16x8 av1 = __builtin_bit_cast(bf16x8, ra[ks8][1]);
            bf16x8 bv[4];
#pragma unroll
            for (int nt = 0; nt < 4; ++nt)
                bv[nt] = *(const bf16x8*)(wb + (ks8 * 4 + nt) * 512);   // imm offset, lane*16B base
#pragma unroll
            for (int nt = 0; nt < 4; ++nt) {
                acc[0][nt] = __builtin_amdgcn_mfma_f32_16x16x32_bf16(av0, bv[nt], acc[0][nt], 0, 0, 0);
                acc[1][nt] = __builtin_amdgcn_mfma_f32_16x16x32_bf16(av1, bv[nt], acc[1][nt], 0, 0, 0);
            }
            if (ks < 24) {                  // keep the 8-deep A pipeline full
                ra[ks8][0] = *(const uint4*)(arow0 + (ks + 8) * 32);
                ra[ks8][1] = *(const uint4*)(arow1 + (ks + 8) * 32);
            }
        }
    }

    // ---- Epilogue: nt is the gate index (i,f,g,o); lane-local LSTM update ----
    float4 cnew[2];
    const float coldv[2][4] = {{cold0.x, cold0.y, cold0.z, cold0.w},
                               {cold1.x, cold1.y, cold1.z, cold1.w}};
#pragma unroll
    for (int mt = 0; mt < 2; ++mt) {
#pragma unroll
        for (int r = 0; r < 4; ++r) {
            const float iv = sigmoid_(acc[mt][0][r] + bi);
            const float fv = sigmoid_(acc[mt][1][r] + bf);
            const float gv = tanh_(acc[mt][2][r] + bg);
            const float ov = sigmoid_(acc[mt][3][r] + bo);
            const float cn = fv * coldv[mt][r] + iv * gv;
            cnew[mt][r] = cn;
            const int rowl = w * 32 + mt * 16 + q * 4 + r;   // 0..255
            Ht[rowl * HSTR + j] = f2bf(ov * tanh_(cn));
        }
    }
    *(float4*)(C + cbase)     = cnew[0];
    *(float4*)(C + cbase + 4) = cnew[1];
    __syncthreads();

    // coalesced h store: 2 threads per row, 16B each (512 thr = 256 rows x 2)
    {
        const int row = tid >> 1, part = tid & 1;
        uint4 v = *(const uint4*)(Ht + row * HSTR + part * 8);
        *(uint4*)(Hout + (size_t)(g * 256 + row) * HPITCH + bn * 16 + part * 8) = v;
    }
}

// Output projection: out[b,t,o] = hs[t+1][b][:] . Wo[o][:] + b_out[o]
__global__ __launch_bounds__(256) void proj_kernel(
    const unsigned short* __restrict__ Hs,   // [T][B][HPITCH] bf16 (slot 1 of hs)
    const unsigned short* __restrict__ Wo,   // [48][E] bf16 (rows >=34 zero)
    const float* __restrict__ b_out,         // [34]
    float* __restrict__ Out)                 // [B][T][34]
{
    __shared__ float red[4][32][OUT_PAD];    // 24 KB

    const int tid = threadIdx.x, wave = tid >> 6, lane = tid & 63;
    const int j = lane & 15, q = lane >> 4;
    const int t  = blockIdx.y;
    const int bb = blockIdx.x;
    const unsigned short* Hbase = Hs + (size_t)t * HSLOT + (size_t)bb * 32 * HPITCH;
    const int k0 = wave * 256;

    f32x4 acc[2][3];
#pragma unroll
    for (int a = 0; a < 2; ++a)
#pragma unroll
        for (int b = 0; b < 3; ++b) acc[a][b] = (f32x4){0.f, 0.f, 0.f, 0.f};

#pragma unroll
    for (int kk = 0; kk < 256; kk += 32) {
        const int kc = k0 + kk + q * 8;
        bf16x8 av[2], bv[3];
#pragma unroll
        for (int mt = 0; mt < 2; ++mt)
            av[mt] = *(const bf16x8*)(Hbase + (size_t)(mt * 16 + j) * HPITCH + kc);
#pragma unroll
        for (int nt = 0; nt < 3; ++nt)
            bv[nt] = *(const bf16x8*)(Wo + (size_t)(nt * 16 + j) * E_DIM + kc);
#pragma unroll
        for (int mt = 0; mt < 2; ++mt)
#pragma unroll
            for (int nt = 0; nt < 3; ++nt)
                acc[mt][nt] = __builtin_amdgcn_mfma_f32_16x16x32_bf16(av[mt], bv[nt], acc[mt][nt], 0, 0, 0);
    }

#pragma unroll
    for (int mt = 0; mt < 2; ++mt)
#pragma unroll
        for (int nt = 0; nt < 3; ++nt)
#pragma unroll
            for (int r = 0; r < 4; ++r)
                red[wave][mt * 16 + q * 4 + r][nt * 16 + j] = acc[mt][nt][r];
    __syncthreads();

#pragma unroll
    for (int ii = 0; ii < 6; ++ii) {
        const int idx = tid * 6 + ii;            // 0..1535 = 32 rows x 48 outs
        const int row = idx / OUT_PAD, o = idx % OUT_PAD;
        if (o < OUT_DIM) {
            const float s = red[0][row][o] + red[1][row][o] + red[2][row][o] + red[3][row][o];
            Out[((size_t)(bb * 32 + row) * T_STEPS + t) * OUT_DIM + o] = s + b_out[o];
        }
    }
}

extern "C" void kernel_launch(void* const* d_in, const int* in_sizes, int n_in,
                              void* d_out, int out_size, void* d_ws, size_t ws_size,
                              hipStream_t stream) {
    (void)in_sizes; (void)n_in; (void)out_size; (void)ws_size;
    const float* h     = (const float*)d_in[0];
    const float* c     = (const float*)d_in[1];
    const float* W_ih  = (const float*)d_in[2];
    const float* W_hh  = (const float*)d_in[3];
    const float* b_ih  = (const float*)d_in[4];
    const float* b_hh  = (const float*)d_in[5];
    const float* W_out = (const float*)d_in[6];
    const float* b_out = (const float*)d_in[7];
    float* out = (float*)d_out;

    char* ws = (char*)d_ws;
    unsigned short* WsumF = (unsigned short*)(ws + 0);          //  8 MB fragment-order
    unsigned short* WhhF  = (unsigned short*)(ws + 8388608);    //  8 MB fragment-order
    float*          bperm = (float*)(ws + 16777216);            // 16 KB
    unsigned short* Woutp = (unsigned short*)(ws + 16842752);   // 96 KB
    float*          cbuf  = (float*)(ws + 16941056);            //  4 MB (MFMA layout)
    unsigned short* hs    = (unsigned short*)(ws + 21135360);   // ~23.4 MB: slot0=h0, slots1..10

    // host-side attribute set (not a stream op; safe under graph capture)
    hipFuncSetAttribute((const void*)lstm_step,
                        hipFuncAttributeMaxDynamicSharedMemorySize, DYN_LDS);

    prep_all<<<2624, 256, 0, stream>>>(W_ih, W_hh, h, c, W_out, b_ih, b_hh,
                                       WsumF, WhhF, hs, Woutp, bperm, cbuf);

    // step 0: x = 0  ->  W_hh only; steps 1..9: x == h_prev -> fused W_ih + W_hh
    lstm_step<<<dim3(64, 4), 512, DYN_LDS, stream>>>(WhhF, bperm, hs, cbuf, hs + HSLOT);
    for (int t = 1; t < T_STEPS; ++t)
        lstm_step<<<dim3(64, 4), 512, DYN_LDS, stream>>>(WsumF, bperm,
                                                         hs + (size_t)t * HSLOT,
                                                         cbuf,
                                                         hs + (size_t)(t + 1) * HSLOT);

    proj_kernel<<<dim3(32, T_STEPS), 256, 0, stream>>>(hs + HSLOT, Woutp, b_out, out);
}